// Round 4
// baseline (21293.767 us; speedup 1.0000x reference)
//
#include <hip/hip_runtime.h>
#include <hip/hip_bf16.h>
#include <stdint.h>

// ---------------------------------------------------------------------------
// Bidirectional 5-layer LSTM (all-sigmoid), B=16, T=1024, D=1024, U=512.
// R6: direction-alternation. Each block owns slice j (16 units) of BOTH
// directions and alternates fwd-step / bwd-step. The h-store -> LLC
// visibility latency of one direction is hidden under the other direction's
// compute; steady-state sentinel polls hit on the first attempt (producer
// stored one full phase ~1500cy earlier). Slices 32->16 units so both
// directions' Uh slices fit LDS (2 x 64KB). Deadlock-free by dataflow
// ordering (store_f precedes any b-wait each iteration; induction on the
// minimal stuck block). Phase barriers are lgkmcnt-only (LDS hazards);
// no vmcnt drain needed since polls don't spin (R5 lesson inapplicable).
// ---------------------------------------------------------------------------

typedef __attribute__((ext_vector_type(8))) short short8;
typedef __attribute__((ext_vector_type(4))) float f32x4;

union U128 { uint4 u; short8 s; };
static __device__ __forceinline__ short8 as_short8(uint4 v) { U128 x; x.u = v; return x.s; }

static __device__ __forceinline__ float sigf(float x) { return 1.0f / (1.0f + __expf(-x)); }

static __device__ __forceinline__ uint32_t f2bfbits(float f) {
  union { float f; uint32_t u; } x; x.f = f;
  return (x.u + 0x7fffu + ((x.u >> 16) & 1u)) >> 16;   // RNE; h in (0,1), no NaN
}
static __device__ __forceinline__ float bflo(uint32_t v) {
  union { uint32_t u; float f; } x; x.u = v << 16; return x.f;
}
static __device__ __forceinline__ float bfhi(uint32_t v) {
  union { uint32_t u; float f; } x; x.u = v & 0xffff0000u; return x.f;
}

// ---------------- x (fp32) -> bf16 ----------------
__global__ __launch_bounds__(256) void f32_to_bf16_k(const float* __restrict__ in,
                                                     __hip_bfloat16* __restrict__ out,
                                                     int n4) {
  int i = blockIdx.x * 256 + threadIdx.x;
  if (i < n4) {
    float4 v = ((const float4*)in)[i];
    uint32_t lo = f2bfbits(v.x) | (f2bfbits(v.y) << 16);
    uint32_t hi = f2bfbits(v.z) | (f2bfbits(v.w) << 16);
    ((uint2*)out)[i] = make_uint2(lo, hi);
  }
}

// ---------------- [2][R][2048] fp32 -> [2][2048][R] bf16 transpose ----------------
__global__ __launch_bounds__(256) void transpose_bf16_k(const float* __restrict__ in,
                                                        __hip_bfloat16* __restrict__ outp,
                                                        int R) {
  __shared__ float tile[64][65];
  int d = blockIdx.z;
  int k0 = blockIdx.x * 64;
  int c0 = blockIdx.y * 64;
  const float* inb = in + (size_t)d * R * 2048;
  __hip_bfloat16* ob = outp + (size_t)d * 2048 * R;
  int col = threadIdx.x & 63, rr = threadIdx.x >> 6;
#pragma unroll
  for (int i = 0; i < 16; ++i) {
    int r = rr + i * 4;
    tile[r][col] = inb[(size_t)(k0 + r) * 2048 + c0 + col];
  }
  __syncthreads();
#pragma unroll
  for (int i = 0; i < 16; ++i) {
    int r = rr + i * 4;
    ob[(size_t)(c0 + r) * R + k0 + col] = __float2bfloat16(tile[col][r]);
  }
}

// ---------------- xz GEMM: y[16384,1024] @ Wt[2][2048,1024]^T + b ----------------
// Output layout: xz[dir][slice(32)][t(1024)][q(4)][b(16)][jj(16)]  (2KB per (dir,slice,t))
__global__ __launch_bounds__(256) void gemm_xz_k(const __hip_bfloat16* __restrict__ y,
                                                 const __hip_bfloat16* __restrict__ Wt,
                                                 const float* __restrict__ bias,
                                                 __hip_bfloat16* __restrict__ xz) {
  __shared__ uint4 Asl[8 * 2 * 64];
  __shared__ uint4 Bsl[8 * 2 * 64];
  int m0 = blockIdx.x * 128;
  int dir = blockIdx.y >> 4;
  int n0 = (blockIdx.y & 15) * 128;
  int tid = threadIdx.x, lane = tid & 63, wv = tid >> 6;
  int wm = wv & 1, wn = wv >> 1;
  const __hip_bfloat16* Wd = Wt + (size_t)dir * 2048 * 1024;
  f32x4 acc[4][4] = {};
  for (int kb = 0; kb < 1024; kb += 64) {
    __syncthreads();
#pragma unroll
    for (int i = 0; i < 4; ++i) {
      int slot = i * 256 + tid;
      int ln = slot & 63, kc = (slot >> 6) & 1, mt = slot >> 7;
      int row = mt * 16 + (ln & 15);
      int kk = kc * 32 + (ln >> 4) * 8;
      Asl[slot] = *(const uint4*)(y + (size_t)(m0 + row) * 1024 + kb + kk);
      Bsl[slot] = *(const uint4*)(Wd + (size_t)(n0 + row) * 1024 + kb + kk);
    }
    __syncthreads();
#pragma unroll
    for (int kc = 0; kc < 2; ++kc) {
      short8 af[4], bf[4];
#pragma unroll
      for (int i = 0; i < 4; ++i) {
        af[i] = as_short8(Asl[((wm * 4 + i) * 2 + kc) * 64 + lane]);
        bf[i] = as_short8(Bsl[((wn * 4 + i) * 2 + kc) * 64 + lane]);
      }
#pragma unroll
      for (int i = 0; i < 4; ++i)
#pragma unroll
        for (int j = 0; j < 4; ++j)
          acc[i][j] = __builtin_amdgcn_mfma_f32_16x16x32_bf16(af[i], bf[j], acc[i][j], 0, 0, 0);
    }
  }
  // epilogue: C/D layout col=lane&15, row=(lane>>4)*4+r  [m89-verified]
  int cq = lane >> 4, cn = lane & 15;
#pragma unroll
  for (int i = 0; i < 4; ++i)
#pragma unroll
    for (int j = 0; j < 4; ++j) {
      int n_g = n0 + (wn * 4 + j) * 16 + cn;
      int q = n_g >> 9, u = n_g & 511, sl = u >> 4, jj = u & 15;
      float bv = bias[dir * 2048 + n_g];
#pragma unroll
      for (int r = 0; r < 4; ++r) {
        int m = m0 + (wm * 4 + i) * 16 + cq * 4 + r;
        int b = m >> 10, t = m & 1023;
        size_t addr = (((size_t)(dir * 32 + sl) * 1024 + t) * 1024) + (q * 16 + b) * 16 + jj;
        xz[addr] = __float2bfloat16(acc[i][j][r] + bv);
      }
    }
}

// ---------------- persistent bidirectional recurrence (alternating) ----------------
// 32 blocks, block = slice (16 units of BOTH dirs).
// LDS: uh 2x64KB = 128KB | hbuf 16x520 bf16 = 16640B | zbuf 16x68 f32 = 4352B |
//      xbuf 1024 bf16 = 2KB  -> 154112 B total.
template <int D>
static __device__ __forceinline__ void lstm_phase(
    int s, int t, int slice, int tid, int lane, int wv, int quad, int l15,
    const uint4* uh, __hip_bfloat16* hbuf, float* zbuf, __hip_bfloat16* xbuf,
    const __hip_bfloat16* __restrict__ xz, __hip_bfloat16* __restrict__ ynext,
    float* __restrict__ outf, uint2& xcur, float& c0, float& c1) {
  // prefetch next t of this direction (overlaps everything below)
  uint2 xn = xcur;
  if (s < 1023) {
    int tn = D ? (t - 1) : (t + 1);
    xn = *((const uint2*)(xz + ((size_t)(D * 32 + slice) * 1024 + tn) * 1024) + tid);
  }
  f32x4 z = {};
  if (s > 0) {
    int tprev = D ? (t + 1) : (t - 1);
    // sentinel poll == coalesced h load (64B/thread); steady-state hits 1st try
    unsigned long long hv[8];
    const unsigned long long* gp[8];
#pragma unroll
    for (int i = 0; i < 4; ++i) {
      int v = i * 2048 + tid * 8;
      int b = v >> 9, col = v & 511;
      const unsigned long long* g =
          (const unsigned long long*)(ynext + ((size_t)b * 1024 + tprev) * 1024 + D * 512 + col);
      gp[2 * i] = g; gp[2 * i + 1] = g + 1;
    }
#pragma unroll
    for (int i = 0; i < 8; ++i)
      hv[i] = __hip_atomic_load(gp[i], __ATOMIC_RELAXED, __HIP_MEMORY_SCOPE_AGENT);
    for (;;) {
      bool ok = true;
#pragma unroll
      for (int i = 0; i < 8; ++i)
        ok &= ((uint32_t)hv[i] != 0u) && ((uint32_t)(hv[i] >> 32) != 0u);
      if (ok) break;
#pragma unroll
      for (int i = 0; i < 8; ++i)
        if (((uint32_t)hv[i] == 0u) || ((uint32_t)(hv[i] >> 32) == 0u))
          hv[i] = __hip_atomic_load(gp[i], __ATOMIC_RELAXED, __HIP_MEMORY_SCOPE_AGENT);
    }
#pragma unroll
    for (int i = 0; i < 4; ++i) {
      int v = i * 2048 + tid * 8;
      int b = v >> 9, col = v & 511;
      unsigned long long* lp = (unsigned long long*)(hbuf + b * 520 + col);
      lp[0] = hv[2 * i]; lp[1] = hv[2 * i + 1];
    }
    // BAR1: LDS-only barrier (no vmcnt drain)
    asm volatile("s_waitcnt lgkmcnt(0)\ns_barrier" ::: "memory");
    // wave wv computes gate tile wv: A = h [16b x 512K], B = Uh-slice
#pragma unroll
    for (int kc = 0; kc < 16; ++kc) {
      short8 afrag = *(const short8*)(hbuf + l15 * 520 + kc * 32 + quad * 8);
      z = __builtin_amdgcn_mfma_f32_16x16x32_bf16(
          afrag, as_short8(uh[((D * 4 + wv) * 16 + kc) * 64 + lane]), z, 0, 0, 0);
    }
  }
  // publish z (col=l15=unit, row=quad*4+r=batch); stage xz chunk
#pragma unroll
  for (int r = 0; r < 4; ++r)
    zbuf[(quad * 4 + r) * 68 + wv * 16 + l15] = z[r];
  *(uint2*)(xbuf + tid * 4) = xcur;
  // BAR2: LDS-only barrier
  asm volatile("s_waitcnt lgkmcnt(0)\ns_barrier" ::: "memory");
  if (tid < 128) {
    int pb = tid >> 3, pj = (tid & 7) * 2;
    const float* zb = zbuf + pb * 68;
    uint32_t xi = *(const uint32_t*)(xbuf + (0 * 16 + pb) * 16 + pj);
    uint32_t xf = *(const uint32_t*)(xbuf + (1 * 16 + pb) * 16 + pj);
    uint32_t xg = *(const uint32_t*)(xbuf + (2 * 16 + pb) * 16 + pj);
    uint32_t xo = *(const uint32_t*)(xbuf + (3 * 16 + pb) * 16 + pj);
    float i0 = sigf(zb[pj] + bflo(xi)),      i1 = sigf(zb[pj + 1] + bfhi(xi));
    float f0 = sigf(zb[16 + pj] + bflo(xf)), f1 = sigf(zb[16 + pj + 1] + bfhi(xf));
    float g0 = sigf(zb[32 + pj] + bflo(xg)), g1 = sigf(zb[32 + pj + 1] + bfhi(xg));
    float o0 = sigf(zb[48 + pj] + bflo(xo)), o1 = sigf(zb[48 + pj + 1] + bfhi(xo));
    c0 = f0 * c0 + i0 * g0;
    c1 = f1 * c1 + i1 * g1;
    float h0 = o0 * sigf(c0);
    float h1 = o1 * sigf(c1);
    size_t oidx = ((size_t)pb * 1024 + t) * 1024 + D * 512 + slice * 16 + pj;
    // zero-guard: bump exact-zero bf16 halves to min subnormal (err <= 9e-41)
    uint32_t ha = f2bfbits(h0); ha += (ha == 0u);
    uint32_t hb = f2bfbits(h1); hb += (hb == 0u);
    __hip_atomic_store((uint32_t*)(ynext + oidx), ha | (hb << 16),
                       __ATOMIC_RELAXED, __HIP_MEMORY_SCOPE_AGENT);
    if (outf) { outf[oidx] = h0; outf[oidx + 1] = h1; }
  }
  asm volatile("" ::: "memory");   // pin store before next phase
  // s==0 only: next phase has no BAR1 (no poll), so close the zbuf/xbuf
  // read(gates) vs write(next publish) race with an extra barrier.
  if (s == 0) asm volatile("s_waitcnt lgkmcnt(0)\ns_barrier" ::: "memory");
  xcur = xn;
}

__global__ __launch_bounds__(256) void lstm_rec_k(const __hip_bfloat16* __restrict__ Ut,  // [2][2048][512]
                                                  const __hip_bfloat16* __restrict__ xz,  // [dir][slice][t][1024]
                                                  __hip_bfloat16* __restrict__ ynext,     // [16][1024][1024], pre-zeroed
                                                  float* __restrict__ outf) {             // last layer or null
  extern __shared__ char smem[];
  uint4* uh = (uint4*)smem;                                 // 8192 x 16B (both dirs)
  __hip_bfloat16* hbuf = (__hip_bfloat16*)(smem + 131072);  // [16][520]
  float* zbuf = (float*)(smem + 147712);                    // [16][68]
  __hip_bfloat16* xbuf = (__hip_bfloat16*)(smem + 152064);  // [1024]
  int slice = blockIdx.x;
  int tid = threadIdx.x, lane = tid & 63, wv = tid >> 6;
  int quad = lane >> 4, l15 = lane & 15;

  // fill LDS with Uh slices for BOTH dirs, pre-fragmented.
  // slot = ((d*4 + w)*16 + kc)*64 + ls ; frag: col = ls&15 (unit), k-rows quad
#pragma unroll 4
  for (int i = 0; i < 32; ++i) {
    int slot = i * 256 + tid;
    int ls = slot & 63, kc = (slot >> 6) & 15, w = (slot >> 10) & 3, d = slot >> 12;
    int n_g = w * 512 + slice * 16 + (ls & 15);
    int k = kc * 32 + (ls >> 4) * 8;
    uh[slot] = *(const uint4*)(Ut + ((size_t)d * 2048 + n_g) * 512 + k);
  }
  __syncthreads();

  float cf0 = 0.f, cf1 = 0.f, cb0 = 0.f, cb1 = 0.f;

  uint2 xf = *((const uint2*)(xz + ((size_t)(0 * 32 + slice) * 1024 + 0) * 1024) + tid);
  uint2 xb = *((const uint2*)(xz + ((size_t)(1 * 32 + slice) * 1024 + 1023) * 1024) + tid);

  for (int s = 0; s < 1024; ++s) {
    lstm_phase<0>(s, s,        slice, tid, lane, wv, quad, l15,
                  uh, hbuf, zbuf, xbuf, xz, ynext, outf, xf, cf0, cf1);
    lstm_phase<1>(s, 1023 - s, slice, tid, lane, wv, quad, l15,
                  uh, hbuf, zbuf, xbuf, xz, ynext, outf, xb, cb0, cb1);
  }
}

// ---------------------------------------------------------------------------
extern "C" void kernel_launch(void* const* d_in, const int* in_sizes, int n_in,
                              void* d_out, int out_size, void* d_ws, size_t ws_size,
                              hipStream_t stream) {
  const float* x  = (const float*)d_in[0];   // [16][1024][1024]
  const float* W  = (const float*)d_in[1];   // [5][2][1024][2048]
  const float* Uh = (const float*)d_in[2];   // [5][2][512][2048]
  const float* b  = (const float*)d_in[3];   // [5][2][2048]

  char* ws = (char*)d_ws;
  size_t off = 0;
  __hip_bfloat16* yA = (__hip_bfloat16*)(ws + off); off += (size_t)16 * 1024 * 1024 * 2;
  __hip_bfloat16* yB = (__hip_bfloat16*)(ws + off); off += (size_t)16 * 1024 * 1024 * 2;
  __hip_bfloat16* xz = (__hip_bfloat16*)(ws + off); off += (size_t)2 * 32 * 1024 * 1024 * 2;
  __hip_bfloat16* Wt = (__hip_bfloat16*)(ws + off); off += (size_t)2 * 2048 * 1024 * 2;
  __hip_bfloat16* Ut = (__hip_bfloat16*)(ws + off); off += (size_t)2 * 2048 * 512 * 2;

  f32_to_bf16_k<<<dim3(16384), dim3(256), 0, stream>>>(x, yA, 4194304);
  hipFuncSetAttribute(reinterpret_cast<const void*>(lstm_rec_k),
                      hipFuncAttributeMaxDynamicSharedMemorySize, 154112);
  for (int l = 0; l < 5; ++l) {
    transpose_bf16_k<<<dim3(16, 32, 2), dim3(256), 0, stream>>>(W + (size_t)l * 2 * 1024 * 2048, Wt, 1024);
    transpose_bf16_k<<<dim3(8, 32, 2),  dim3(256), 0, stream>>>(Uh + (size_t)l * 2 * 512 * 2048, Ut, 512);
    __hip_bfloat16* ycur = (l & 1) ? yB : yA;
    __hip_bfloat16* ynxt = (l & 1) ? yA : yB;
    // zero ynxt: sentinel protocol requires unwritten h words to read as 0.
    hipMemsetAsync(ynxt, 0, (size_t)16 * 1024 * 1024 * 2, stream);
    gemm_xz_k<<<dim3(128, 32), dim3(256), 0, stream>>>(ycur, Wt, b + (size_t)l * 2 * 2048, xz);
    lstm_rec_k<<<dim3(32), dim3(256), 154112, stream>>>(
        Ut, xz, ynxt, (l == 4) ? (float*)d_out : nullptr);
  }
}